// Round 7
// baseline (65.772 us; speedup 1.0000x reference)
//
#include <hip/hip_runtime.h>

#define NN 128   // modes

// Folded per-layer MMI coefficients: a = A*e^{i th}, b = iB*e^{i th}
struct Coef { float2 a0, b0, a1, b1; };

__device__ __forceinline__ Coef make_coef(float2 th) {
    const float A = sqrtf(0.95f * 0.505f);
    const float B = sqrtf(0.95f * 0.495f);
    float s0, c0, s1, c1;
    __sincosf(th.x, &s0, &c0);
    __sincosf(th.y, &s1, &c1);
    Coef cf;
    cf.a0 = make_float2(A * c0, A * s0);
    cf.b0 = make_float2(-B * s0, B * c0);
    cf.a1 = make_float2(A * c1, A * s1);
    cf.b1 = make_float2(-B * s1, B * c1);
    return cf;
}

// folded diag+MMI layer: n0 = a0*v0 + iB*v1 ; n1 = b0*v0 + A*v1 (3-FMA dots)
__device__ __forceinline__ void mmi_layer(const Coef& cf, float A, float B,
                                          float2& v0, float2& v1,
                                          float2& v2, float2& v3) {
    float2 n0, n1, n2, n3;
    n0.x = cf.a0.x * v0.x - cf.a0.y * v0.y - B * v1.y;
    n0.y = cf.a0.x * v0.y + cf.a0.y * v0.x + B * v1.x;
    n1.x = cf.b0.x * v0.x - cf.b0.y * v0.y + A * v1.x;
    n1.y = cf.b0.x * v0.y + cf.b0.y * v0.x + A * v1.y;
    n2.x = cf.a1.x * v2.x - cf.a1.y * v2.y - B * v3.y;
    n2.y = cf.a1.x * v2.y + cf.a1.y * v2.x + B * v3.x;
    n3.x = cf.b1.x * v2.x - cf.b1.y * v2.y + A * v3.x;
    n3.y = cf.b1.x * v2.y + cf.b1.y * v2.x + A * v3.y;
    v0 = n0; v1 = n1; v2 = n2; v3 = n3;
}

// CROSS: (v1,v2) lane-local; (v3_l, v0_{l+1}) cross-lane; corners *= S2
__device__ __forceinline__ void cross_layer(float C2, float S2, int l,
                                            float2& v0, float2& v1,
                                            float2& v2, float2& v3) {
    float2 m0, m1, m2, m3;
    m1.x = C2 * v1.x - S2 * v2.y;  m1.y = C2 * v1.y + S2 * v2.x;
    m2.x = C2 * v2.x - S2 * v1.y;  m2.y = C2 * v2.y + S2 * v1.x;
    float nxt_re = __shfl_down(v0.x, 1);
    float nxt_im = __shfl_down(v0.y, 1);
    float prv_re = __shfl_up(v3.x, 1);
    float prv_im = __shfl_up(v3.y, 1);
    m3 = (l == 63) ? make_float2(S2 * v3.x, S2 * v3.y)
                   : make_float2(C2 * v3.x - S2 * nxt_im, C2 * v3.y + S2 * nxt_re);
    m0 = (l == 0)  ? make_float2(S2 * v0.x, S2 * v0.y)
                   : make_float2(C2 * v0.x - S2 * prv_im, C2 * v0.y + S2 * prv_re);
    v0 = m0; v1 = m1; v2 = m2; v3 = m3;
}

// One wave per COLUMN PAIR (2b, 2b+1). Lane l holds rows 4l..4l+3 of both
// columns (16 f32 state regs). Coefficients shared across the pair; the two
// independent dependency chains fill each other's stall slots (single wave
// per SIMD, in-order issue). Output: Re(T[n][c]) f32 row-major.
__global__ __launch_bounds__(64) void mesh_kernel(
    const float* __restrict__ theta_in,    // (128,)
    const float* __restrict__ theta_even,  // (255,128)
    const float* __restrict__ theta_out,   // (128,)
    float* __restrict__ out)               // (128,128) f32 = Re(arch)
{
    const int b = blockIdx.x;   // column pair: cA = 2b, cB = 2b+1
    const int l = threadIdx.x;

    const float A  = sqrtf(0.95f * 0.505f);
    const float B  = sqrtf(0.95f * 0.495f);
    const float C2 = sqrtf(0.98f * 0.01f);
    const float S2 = sqrtf(0.98f * 0.99f);

    // prologue loads
    const float2* tev = (const float2*)(theta_even) + l;  // float2 idx: j*64 + l
    float2 th0 = tev[0];
    float2 tn1 = tev[64];
    float2 tn2 = tev[2 * 64];
    float2 tn3 = tev[3 * 64];
    float2 tho = ((const float2*)theta_out)[l];           // theta_out[2l], [2l+1]
    float2 thi = ((const float2*)theta_in)[b];            // theta_in[2b], [2b+1]

    // init after MMI_IN: col 2b -> lane b slots (v0,v1); col 2b+1 -> lane b slots (v2,v3)
    float2 a0 = make_float2(0.f, 0.f), a1 = a0, a2 = a0, a3 = a0;   // column A state
    float2 b0 = a0, b1 = a0, b2 = a0, b3 = a0;                      // column B state
    {
        float s, co;
        __sincosf(thi.x, &s, &co);
        if (l == b) { a0 = make_float2(A * co, A * s); a1 = make_float2(-B * s, B * co); }
        __sincosf(thi.y, &s, &co);
        if (l == b) { b2 = make_float2(A * co, A * s); b3 = make_float2(-B * s, B * co); }
    }

    Coef cf = make_coef(th0);   // layer 0 coefficients (shared by both columns)

    #pragma unroll 2
    for (int j = 0; j < 254; ++j) {
        int jl = j + 4; if (jl > 254) jl = 254;
        float2 th_load = tev[jl * 64];       // distance-4 theta prefetch

        Coef cfn = make_coef(tn1);           // next layer's coefs, off the state chain

        mmi_layer(cf, A, B, a0, a1, a2, a3);
        mmi_layer(cf, A, B, b0, b1, b2, b3);

        if (!(j & 1)) {
            cross_layer(C2, S2, l, a0, a1, a2, a3);
            cross_layer(C2, S2, l, b0, b1, b2, b3);
        }

        tn1 = tn2; tn2 = tn3; tn3 = th_load;
        cf = cfn;
    }

    // Exit: cf = coef(theta[254]); final diag+MMI_OUT is the same folded form:
    // row 2l:  a0c*v0 + iB*v1 ; row 2l+1: a1c*v2 + iB*v3
    float2 oA0, oA1, oB0, oB1;
    oA0.x = cf.a0.x * a0.x - cf.a0.y * a0.y - B * a1.y;
    oA0.y = cf.a0.x * a0.y + cf.a0.y * a0.x + B * a1.x;
    oA1.x = cf.a1.x * a2.x - cf.a1.y * a2.y - B * a3.y;
    oA1.y = cf.a1.x * a2.y + cf.a1.y * a2.x + B * a3.x;
    oB0.x = cf.a0.x * b0.x - cf.a0.y * b0.y - B * b1.y;
    oB0.y = cf.a0.x * b0.y + cf.a0.y * b0.x + B * b1.x;
    oB1.x = cf.a1.x * b2.x - cf.a1.y * b2.y - B * b3.y;
    oB1.y = cf.a1.x * b2.y + cf.a1.y * b2.x + B * b3.x;

    // diag(d_out) rotation (per-ROW, shared by both columns); keep real part
    float so0, co0, so1, co1;
    __sincosf(tho.x, &so0, &co0);
    __sincosf(tho.y, &so1, &co1);
    float2 r0 = make_float2(co0 * oA0.x - so0 * oA0.y,   // row 2l,   cols 2b / 2b+1
                            co0 * oB0.x - so0 * oB0.y);
    float2 r1 = make_float2(co1 * oA1.x - so1 * oA1.y,   // row 2l+1, cols 2b / 2b+1
                            co1 * oB1.x - so1 * oB1.y);

    *(float2*)(out + (2 * l)     * NN + 2 * b) = r0;
    *(float2*)(out + (2 * l + 1) * NN + 2 * b) = r1;
}

extern "C" void kernel_launch(void* const* d_in, const int* in_sizes, int n_in,
                              void* d_out, int out_size, void* d_ws, size_t ws_size,
                              hipStream_t stream) {
    // Identify inputs by SIZE: theta_even is the unique large (32640) array;
    // the two 128-elem arrays keep relative order (theta_in before theta_out).
    int ev = 0;
    for (int i = 0; i < n_in; ++i) if (in_sizes[i] > 1000) ev = i;
    int a = -1, b = -1;
    for (int i = 0; i < n_in; ++i) {
        if (i == ev) continue;
        if (a < 0) a = i; else if (b < 0) b = i;
    }
    const float* th_in  = (const float*)d_in[a];
    const float* th_ev  = (const float*)d_in[ev];
    const float* th_out = (const float*)d_in[b];
    mesh_kernel<<<dim3(NN / 2), dim3(64), 0, stream>>>(th_in, th_ev, th_out, (float*)d_out);
}

// Round 9
// 64.694 us; speedup vs baseline: 1.0167x; 1.0167x over previous
//
#include <hip/hip_runtime.h>

#define NN 128   // modes

// ---- whole-wave lane shifts via DPP (GCN/CDNA wave_shl/wave_shr) ----
// wave_shl:1 (0x130): lane i <- lane i+1 ; wave_shr:1 (0x138): lane i <- lane i-1
// bound_ctrl=false + old=src: edge lanes keep their own value (zeroed by es coeff).
__device__ __forceinline__ float wshl1(float x) {
    return __int_as_float(__builtin_amdgcn_update_dpp(
        __float_as_int(x), __float_as_int(x), 0x130, 0xf, 0xf, false));
}
__device__ __forceinline__ float wshr1(float x) {
    return __int_as_float(__builtin_amdgcn_update_dpp(
        __float_as_int(x), __float_as_int(x), 0x138, 0xf, 0xf, false));
}

// Folded per-layer coefficients for 4 MMI pairs: a_k = A e^{i th_k}, b_k = iB e^{i th_k}
struct Coef { float2 a[4]; float2 b[4]; };

__device__ __forceinline__ Coef make_coef(float4 th) {
    const float A = sqrtf(0.95f * 0.505f);
    const float B = sqrtf(0.95f * 0.495f);
    Coef cf;
    float s, c;
    __sincosf(th.x, &s, &c); cf.a[0] = make_float2(A*c, A*s); cf.b[0] = make_float2(-B*s, B*c);
    __sincosf(th.y, &s, &c); cf.a[1] = make_float2(A*c, A*s); cf.b[1] = make_float2(-B*s, B*c);
    __sincosf(th.z, &s, &c); cf.a[2] = make_float2(A*c, A*s); cf.b[2] = make_float2(-B*s, B*c);
    __sincosf(th.w, &s, &c); cf.a[3] = make_float2(A*c, A*s); cf.b[3] = make_float2(-B*s, B*c);
    return cf;
}

// folded diag+MMI on one pair: u' = a*u + iB*w ; w' = b*u + A*w
__device__ __forceinline__ void mmi_pair(float2 a, float2 bc, float A, float B,
                                         float2& u, float2& w) {
    float2 n0, n1;
    n0.x = a.x*u.x - a.y*u.y - B*w.y;
    n0.y = a.x*u.y + a.y*u.x + B*w.x;
    n1.x = bc.x*u.x - bc.y*u.y + A*w.x;
    n1.y = bc.x*u.y + bc.y*u.x + A*w.y;
    u = n0; w = n1;
}

// CROSS on a lane-local pair: u' = C2*u + iS2*w ; w' = C2*w + iS2*u
__device__ __forceinline__ void cross_pair(float C2, float S2, float2& u, float2& w) {
    float2 m1, m2;
    m1.x = C2*u.x - S2*w.y; m1.y = C2*u.y + S2*w.x;
    m2.x = C2*w.x - S2*u.y; m2.y = C2*w.y + S2*u.x;
    u = m1; w = m2;
}

// One wave per COLUMN PAIR. Lanes 0-31: column 2b; lanes 32-63: column 2b+1.
// Lane (h=l>>5, r=l&31) holds global rows 8r..8r+7 (8 complex = 16 f32 regs).
// All cross-lane traffic via whole-wave DPP shifts (zero DS instructions).
__global__ __launch_bounds__(64) void mesh_kernel(
    const float* __restrict__ theta_in,    // (128,)
    const float* __restrict__ theta_even,  // (255,128)
    const float* __restrict__ theta_out,   // (128,)
    float* __restrict__ out)               // (128,128) f32 = Re(arch)
{
    const int b = blockIdx.x;        // column pair: 2b (low half), 2b+1 (high half)
    const int l = threadIdx.x;
    const int r = l & 31;            // row-block index within column
    const int h = l >> 5;            // which column of the pair

    const float A  = sqrtf(0.95f * 0.505f);
    const float B  = sqrtf(0.95f * 0.495f);
    const float C2 = sqrtf(0.98f * 0.01f);
    const float S2 = sqrtf(0.98f * 0.99f);

    // branchless corner coefficients: global row 0 (lane r==0, slot v0) and
    // row 255 (lane r==31, slot v7) pass with S2 and ZERO neighbor weight —
    // this also kills the cross-column leak of the wave-wide DPP shifts at
    // lanes 0/32 (shr) and 31/63 (shl).
    const float ec0 = (r == 0)  ? S2 : C2, es0 = (r == 0)  ? 0.f : S2;
    const float ec7 = (r == 31) ? S2 : C2, es7 = (r == 31) ? 0.f : S2;

    // theta pipeline: lane needs phases for its even rows 8r,8r+2,8r+4,8r+6
    // = theta_even[j*128 + 4r .. 4r+3] -> float4 at ((float4*)theta_even)[j*32 + r]
    const float4* tev = ((const float4*)theta_even) + r;
    float4 th0 = tev[0];
    float4 tn1 = tev[32];
    float4 tn2 = tev[2 * 32];
    float4 tn3 = tev[3 * 32];

    // ---- init: column c=2b+h excited at rows 4b+2h, 4b+2h+1 after MMI_IN ----
    float2 v0 = make_float2(0.f,0.f), v1=v0, v2=v0, v3=v0, v4=v0, v5=v0, v6=v0, v7=v0;
    {
        float2 thi2 = ((const float2*)theta_in)[b];
        float thin = h ? thi2.y : thi2.x;
        float s, c;
        __sincosf(thin, &s, &c);
        float2 e0 = make_float2(A*c, A*s);      // A e^{i th}
        float2 e1 = make_float2(-B*s, B*c);     // iB e^{i th}
        int s0i = ((b & 1) << 2) | (h << 1);    // slot 0,2,4,6
        if (r == (b >> 1)) {
            if      (s0i == 0) { v0 = e0; v1 = e1; }
            else if (s0i == 2) { v2 = e0; v3 = e1; }
            else if (s0i == 4) { v4 = e0; v5 = e1; }
            else               { v6 = e0; v7 = e1; }
        }
    }

    Coef cf = make_coef(th0);

    for (int jj = 0; jj < 127; ++jj) {
        const int j = 2 * jj;

        // ================= even layer j: MMI + CROSS =================
        {
            int jl = j + 4; if (jl > 254) jl = 254;
            float4 th_load = tev[jl * 32];
            Coef cfn = make_coef(tn1);           // next layer's coefs, off the state chain

            mmi_pair(cf.a[0], cf.b[0], A, B, v0, v1);
            mmi_pair(cf.a[1], cf.b[1], A, B, v2, v3);
            mmi_pair(cf.a[2], cf.b[2], A, B, v4, v5);
            mmi_pair(cf.a[3], cf.b[3], A, B, v6, v7);

            // neighbor values: nxt = lane r+1's v0 ; prv = lane r-1's v7
            float nx = wshl1(v0.x), ny = wshl1(v0.y);
            float px = wshr1(v7.x), py = wshr1(v7.y);

            float2 m0, m7;
            m0.x = ec0*v0.x - es0*py;  m0.y = ec0*v0.y + es0*px;   // + i*es0*prv
            m7.x = ec7*v7.x - es7*ny;  m7.y = ec7*v7.y + es7*nx;   // + i*es7*nxt
            cross_pair(C2, S2, v1, v2);
            cross_pair(C2, S2, v3, v4);
            cross_pair(C2, S2, v5, v6);
            v0 = m0; v7 = m7;

            tn1 = tn2; tn2 = tn3; tn3 = th_load;
            cf = cfn;
        }

        // ================= odd layer j+1: MMI only =================
        {
            int jl = j + 5; if (jl > 254) jl = 254;
            float4 th_load = tev[jl * 32];
            Coef cfn = make_coef(tn1);

            mmi_pair(cf.a[0], cf.b[0], A, B, v0, v1);
            mmi_pair(cf.a[1], cf.b[1], A, B, v2, v3);
            mmi_pair(cf.a[2], cf.b[2], A, B, v4, v5);
            mmi_pair(cf.a[3], cf.b[3], A, B, v6, v7);

            tn1 = tn2; tn2 = tn3; tn3 = th_load;
            cf = cfn;
        }
    }

    // ---- exit: cf = coef(theta[254]); final diag+MMI_OUT (folded) ----
    float2 o0, o1, o2, o3;
    o0.x = cf.a[0].x*v0.x - cf.a[0].y*v0.y - B*v1.y;
    o0.y = cf.a[0].x*v0.y + cf.a[0].y*v0.x + B*v1.x;
    o1.x = cf.a[1].x*v2.x - cf.a[1].y*v2.y - B*v3.y;
    o1.y = cf.a[1].x*v2.y + cf.a[1].y*v2.x + B*v3.x;
    o2.x = cf.a[2].x*v4.x - cf.a[2].y*v4.y - B*v5.y;
    o2.y = cf.a[2].x*v4.y + cf.a[2].y*v4.x + B*v5.x;
    o3.x = cf.a[3].x*v6.x - cf.a[3].y*v6.y - B*v7.y;
    o3.y = cf.a[3].x*v6.y + cf.a[3].y*v6.x + B*v7.x;

    // diag(d_out) per output row (rows 4r..4r+3), keep real part
    float4 tho = ((const float4*)theta_out)[r];
    float s, c;
    const int col = 2 * b + h;
    __sincosf(tho.x, &s, &c); out[(4*r + 0) * NN + col] = c*o0.x - s*o0.y;
    __sincosf(tho.y, &s, &c); out[(4*r + 1) * NN + col] = c*o1.x - s*o1.y;
    __sincosf(tho.z, &s, &c); out[(4*r + 2) * NN + col] = c*o2.x - s*o2.y;
    __sincosf(tho.w, &s, &c); out[(4*r + 3) * NN + col] = c*o3.x - s*o3.y;
}

extern "C" void kernel_launch(void* const* d_in, const int* in_sizes, int n_in,
                              void* d_out, int out_size, void* d_ws, size_t ws_size,
                              hipStream_t stream) {
    // Identify inputs by SIZE: theta_even is the unique large (32640) array;
    // the two 128-elem arrays keep relative order (theta_in before theta_out).
    int ev = 0;
    for (int i = 0; i < n_in; ++i) if (in_sizes[i] > 1000) ev = i;
    int a = -1, b = -1;
    for (int i = 0; i < n_in; ++i) {
        if (i == ev) continue;
        if (a < 0) a = i; else if (b < 0) b = i;
    }
    const float* th_in  = (const float*)d_in[a];
    const float* th_ev  = (const float*)d_in[ev];
    const float* th_out = (const float*)d_in[b];
    mesh_kernel<<<dim3(NN / 2), dim3(64), 0, stream>>>(th_in, th_ev, th_out, (float*)d_out);
}

// Round 10
// 42.478 us; speedup vs baseline: 1.5484x; 1.5230x over previous
//
#include <hip/hip_runtime.h>

#define NN 128   // modes

// ---- whole-wave lane shifts via DPP (wave_shl:1 / wave_shr:1) ----
// bound_ctrl=false + old=src: edge lanes keep own value (zeroed by es coeff).
__device__ __forceinline__ float wshl1(float x) {   // lane i <- lane i+1
    return __int_as_float(__builtin_amdgcn_update_dpp(
        __float_as_int(x), __float_as_int(x), 0x130, 0xf, 0xf, false));
}
__device__ __forceinline__ float wshr1(float x) {   // lane i <- lane i-1
    return __int_as_float(__builtin_amdgcn_update_dpp(
        __float_as_int(x), __float_as_int(x), 0x138, 0xf, 0xf, false));
}

#define KA  0.69277705f            // sqrt(0.95*0.505)  (folded below via constexpr-like consts)

// ---------------- kernel 1: coefficient table ----------------
// tab[j*128+m] = (A cos th, A sin th, B cos th, B sin th) for th = theta_even[j,m]
__global__ __launch_bounds__(256) void coef_kernel(
    const float* __restrict__ th_ev, float4* __restrict__ tab)
{
    const float A = sqrtf(0.95f * 0.505f);
    const float B = sqrtf(0.95f * 0.495f);
    int i = blockIdx.x * 256 + threadIdx.x;
    if (i < 255 * 128) {
        float s, c;
        __sincosf(th_ev[i], &s, &c);
        tab[i] = make_float4(A * c, A * s, B * c, B * s);
    }
}

// ---------------- kernel 2: mesh evolution (table-driven) ----------------
// One wave per column c. Lane l holds rows 4l..4l+3 (4 complex). Inner loop is
// pure FMA + 2 float4 table loads/layer, prefetched 4 deep via unroll-4 buffer
// (compile-time slot indices -> no register rotation, no vmcnt(0) collapse).
__global__ __launch_bounds__(64) void mesh_tab_kernel(
    const float4* __restrict__ tab,        // (255*128) coef table
    const float* __restrict__ theta_in,    // (128,)
    const float* __restrict__ theta_out,   // (128,)
    float* __restrict__ out)               // (128,128) f32 = Re(arch)
{
    const int c = blockIdx.x;
    const int l = threadIdx.x;

    const float A  = sqrtf(0.95f * 0.505f);
    const float B  = sqrtf(0.95f * 0.495f);
    const float C2 = sqrtf(0.98f * 0.01f);
    const float S2 = sqrtf(0.98f * 0.99f);

    // branchless corner coeffs: row 0 (l==0, slot v0), row 255 (l==63, slot v3)
    const float ec0 = (l == 0)  ? S2 : C2, es0 = (l == 0)  ? 0.f : S2;
    const float ec3 = (l == 63) ? S2 : C2, es3 = (l == 63) ? 0.f : S2;

    // init: column c after MMI_IN -> rows 2c: A e^{i th}, 2c+1: iB e^{i th}
    float2 v0 = make_float2(0.f, 0.f), v1 = v0, v2 = v0, v3 = v0;
    {
        float s, co;
        __sincosf(theta_in[c], &s, &co);
        float2 e0 = make_float2(A * co, A * s);
        float2 e1 = make_float2(-B * s, B * co);
        if (l == (c >> 1)) {
            if (c & 1) { v2 = e0; v3 = e1; }
            else       { v0 = e0; v1 = e1; }
        }
    }

    // lane l consumes tab[j*128 + 2l] (rows 4l,4l+1) and tab[j*128 + 2l+1]
    const float4* TB = tab + 2 * l;

    float4 bA[4], bB[4];
    #pragma unroll
    for (int p = 0; p < 4; ++p) { bA[p] = TB[p * 128]; bB[p] = TB[p * 128 + 1]; }

    // folded diag+MMI: n0 = a*v0 + iB*v1 ; n1 = b*v0 + A*v1, a=(x,y), b=(-w,z)
    auto mmi2 = [&](const float4 cA, const float4 cB) {
        float2 n0, n1, n2, n3;
        n0.x =  cA.x * v0.x - cA.y * v0.y - B * v1.y;
        n0.y =  cA.x * v0.y + cA.y * v0.x + B * v1.x;
        n1.x = -cA.w * v0.x - cA.z * v0.y + A * v1.x;
        n1.y = -cA.w * v0.y + cA.z * v0.x + A * v1.y;
        n2.x =  cB.x * v2.x - cB.y * v2.y - B * v3.y;
        n2.y =  cB.x * v2.y + cB.y * v2.x + B * v3.x;
        n3.x = -cB.w * v2.x - cB.z * v2.y + A * v3.x;
        n3.y = -cB.w * v2.y + cB.z * v2.x + A * v3.y;
        v0 = n0; v1 = n1; v2 = n2; v3 = n3;
    };
    auto crossl = [&]() {
        float nx = wshl1(v0.x), ny = wshl1(v0.y);   // lane l+1's v0
        float px = wshr1(v3.x), py = wshr1(v3.y);   // lane l-1's v3
        float2 m0, m1, m2, m3;
        m0.x = ec0 * v0.x - es0 * py;  m0.y = ec0 * v0.y + es0 * px;
        m3.x = ec3 * v3.x - es3 * ny;  m3.y = ec3 * v3.y + es3 * nx;
        m1.x = C2 * v1.x - S2 * v2.y;  m1.y = C2 * v1.y + S2 * v2.x;
        m2.x = C2 * v2.x - S2 * v1.y;  m2.y = C2 * v2.y + S2 * v1.x;
        v0 = m0; v1 = m1; v2 = m2; v3 = m3;
    };

    #pragma unroll 4
    for (int j = 0; j < 252; ++j) {
        const int p = j & 3;                 // compile-time per unrolled copy
        float4 cA = bA[p], cB = bB[p];
        int jl = j + 4; if (jl > 254) jl = 254;
        bA[p] = TB[jl * 128];                // loads write consume-slot directly
        bB[p] = TB[jl * 128 + 1];
        mmi2(cA, cB);
        if ((j & 1) == 0) crossl();
    }
    // j = 252 (even: MMI+CROSS), j = 253 (odd: MMI) — buf slots 0,1
    { float4 cA = bA[0], cB = bB[0]; mmi2(cA, cB); crossl(); }
    { float4 cA = bA[1], cB = bB[1]; mmi2(cA, cB); }

    // layer 254 coefs: slot 2 was last written at j=250 with jl=254
    float4 cA = bA[2], cB = bB[2];
    float2 o0, o1;   // final diag + MMI_OUT (folded): row 2l, 2l+1
    o0.x = cA.x * v0.x - cA.y * v0.y - B * v1.y;
    o0.y = cA.x * v0.y + cA.y * v0.x + B * v1.x;
    o1.x = cB.x * v2.x - cB.y * v2.y - B * v3.y;
    o1.y = cB.x * v2.y + cB.y * v2.x + B * v3.x;

    // diag(d_out) rotation, keep real part
    float2 tho = ((const float2*)theta_out)[l];
    float s0, c0, s1, c1;
    __sincosf(tho.x, &s0, &c0);
    __sincosf(tho.y, &s1, &c1);
    out[(2 * l)     * NN + c] = c0 * o0.x - s0 * o0.y;
    out[(2 * l + 1) * NN + c] = c1 * o1.x - s1 * o1.y;
}

// ---------------- fallback (R6, self-contained, proven): used if ws too small ----------------
struct CoefF { float2 a0, b0, a1, b1; };
__device__ __forceinline__ CoefF make_coef_f(float2 th) {
    const float A = sqrtf(0.95f * 0.505f);
    const float B = sqrtf(0.95f * 0.495f);
    float s0, c0, s1, c1;
    __sincosf(th.x, &s0, &c0);
    __sincosf(th.y, &s1, &c1);
    CoefF cf;
    cf.a0 = make_float2(A * c0, A * s0); cf.b0 = make_float2(-B * s0, B * c0);
    cf.a1 = make_float2(A * c1, A * s1); cf.b1 = make_float2(-B * s1, B * c1);
    return cf;
}
__global__ __launch_bounds__(64) void mesh_fallback(
    const float* __restrict__ theta_in, const float* __restrict__ theta_even,
    const float* __restrict__ theta_out, float* __restrict__ out)
{
    const int c = blockIdx.x, l = threadIdx.x;
    const float A  = sqrtf(0.95f * 0.505f);
    const float B  = sqrtf(0.95f * 0.495f);
    const float C2 = sqrtf(0.98f * 0.01f);
    const float S2 = sqrtf(0.98f * 0.99f);
    const float ec0 = (l == 0)  ? S2 : C2, es0 = (l == 0)  ? 0.f : S2;
    const float ec3 = (l == 63) ? S2 : C2, es3 = (l == 63) ? 0.f : S2;
    float2 v0 = make_float2(0.f, 0.f), v1 = v0, v2 = v0, v3 = v0;
    {
        float s, co; __sincosf(theta_in[c], &s, &co);
        if (l == (c >> 1)) {
            float2 e0 = make_float2(A * co, A * s), e1 = make_float2(-B * s, B * co);
            if (c & 1) { v2 = e0; v3 = e1; } else { v0 = e0; v1 = e1; }
        }
    }
    const float2* tev = (const float2*)theta_even + l;
    float2 tb[4];
    #pragma unroll
    for (int p = 0; p < 4; ++p) tb[p] = tev[p * 64];
    #pragma unroll 4
    for (int j = 0; j < 252; ++j) {
        const int p = j & 3;
        float2 th = tb[p];
        int jl = j + 4; if (jl > 254) jl = 254;
        tb[p] = tev[jl * 64];
        CoefF cf = make_coef_f(th);
        float2 n0, n1, n2, n3;
        n0.x = cf.a0.x*v0.x - cf.a0.y*v0.y - B*v1.y;  n0.y = cf.a0.x*v0.y + cf.a0.y*v0.x + B*v1.x;
        n1.x = cf.b0.x*v0.x - cf.b0.y*v0.y + A*v1.x;  n1.y = cf.b0.x*v0.y + cf.b0.y*v0.x + A*v1.y;
        n2.x = cf.a1.x*v2.x - cf.a1.y*v2.y - B*v3.y;  n2.y = cf.a1.x*v2.y + cf.a1.y*v2.x + B*v3.x;
        n3.x = cf.b1.x*v2.x - cf.b1.y*v2.y + A*v3.x;  n3.y = cf.b1.x*v2.y + cf.b1.y*v2.x + A*v3.y;
        v0 = n0; v1 = n1; v2 = n2; v3 = n3;
        if ((j & 1) == 0) {
            float nx = wshl1(v0.x), ny = wshl1(v0.y);
            float px = wshr1(v3.x), py = wshr1(v3.y);
            float2 m0, m1, m2, m3;
            m0.x = ec0*v0.x - es0*py;  m0.y = ec0*v0.y + es0*px;
            m3.x = ec3*v3.x - es3*ny;  m3.y = ec3*v3.y + es3*nx;
            m1.x = C2*v1.x - S2*v2.y;  m1.y = C2*v1.y + S2*v2.x;
            m2.x = C2*v2.x - S2*v1.y;  m2.y = C2*v2.y + S2*v1.x;
            v0 = m0; v1 = m1; v2 = m2; v3 = m3;
        }
    }
    for (int j = 252; j < 254; ++j) {
        CoefF cf = make_coef_f(tb[j & 3]);
        float2 n0, n1, n2, n3;
        n0.x = cf.a0.x*v0.x - cf.a0.y*v0.y - B*v1.y;  n0.y = cf.a0.x*v0.y + cf.a0.y*v0.x + B*v1.x;
        n1.x = cf.b0.x*v0.x - cf.b0.y*v0.y + A*v1.x;  n1.y = cf.b0.x*v0.y + cf.b0.y*v0.x + A*v1.y;
        n2.x = cf.a1.x*v2.x - cf.a1.y*v2.y - B*v3.y;  n2.y = cf.a1.x*v2.y + cf.a1.y*v2.x + B*v3.x;
        n3.x = cf.b1.x*v2.x - cf.b1.y*v2.y + A*v3.x;  n3.y = cf.b1.x*v2.y + cf.b1.y*v2.x + A*v3.y;
        v0 = n0; v1 = n1; v2 = n2; v3 = n3;
        if ((j & 1) == 0) {
            float nx = wshl1(v0.x), ny = wshl1(v0.y);
            float px = wshr1(v3.x), py = wshr1(v3.y);
            float2 m0, m1, m2, m3;
            m0.x = ec0*v0.x - es0*py;  m0.y = ec0*v0.y + es0*px;
            m3.x = ec3*v3.x - es3*ny;  m3.y = ec3*v3.y + es3*nx;
            m1.x = C2*v1.x - S2*v2.y;  m1.y = C2*v1.y + S2*v2.x;
            m2.x = C2*v2.x - S2*v1.y;  m2.y = C2*v2.y + S2*v1.x;
            v0 = m0; v1 = m1; v2 = m2; v3 = m3;
        }
    }
    CoefF cf = make_coef_f(tb[254 & 3]);
    float2 o0, o1;
    o0.x = cf.a0.x*v0.x - cf.a0.y*v0.y - B*v1.y;  o0.y = cf.a0.x*v0.y + cf.a0.y*v0.x + B*v1.x;
    o1.x = cf.a1.x*v2.x - cf.a1.y*v2.y - B*v3.y;  o1.y = cf.a1.x*v2.y + cf.a1.y*v2.x + B*v3.x;
    float2 tho = ((const float2*)theta_out)[l];
    float s0, c0, s1, c1;
    __sincosf(tho.x, &s0, &c0);
    __sincosf(tho.y, &s1, &c1);
    out[(2 * l)     * NN + c] = c0 * o0.x - s0 * o0.y;
    out[(2 * l + 1) * NN + c] = c1 * o1.x - s1 * o1.y;
}

extern "C" void kernel_launch(void* const* d_in, const int* in_sizes, int n_in,
                              void* d_out, int out_size, void* d_ws, size_t ws_size,
                              hipStream_t stream) {
    // Identify inputs by SIZE: theta_even is the unique large (32640) array;
    // the two 128-elem arrays keep relative order (theta_in before theta_out).
    int ev = 0;
    for (int i = 0; i < n_in; ++i) if (in_sizes[i] > 1000) ev = i;
    int a = -1, b = -1;
    for (int i = 0; i < n_in; ++i) {
        if (i == ev) continue;
        if (a < 0) a = i; else if (b < 0) b = i;
    }
    const float* th_in  = (const float*)d_in[a];
    const float* th_ev  = (const float*)d_in[ev];
    const float* th_out = (const float*)d_in[b];

    const size_t tab_bytes = (size_t)255 * 128 * sizeof(float4);   // 522240
    if (ws_size >= tab_bytes) {
        float4* tab = (float4*)d_ws;
        coef_kernel<<<dim3(128), dim3(256), 0, stream>>>(th_ev, tab);
        mesh_tab_kernel<<<dim3(NN), dim3(64), 0, stream>>>(tab, th_in, th_out, (float*)d_out);
    } else {
        mesh_fallback<<<dim3(NN), dim3(64), 0, stream>>>(th_in, th_ev, th_out, (float*)d_out);
    }
}

// Round 11
// 37.515 us; speedup vs baseline: 1.7532x; 1.1323x over previous
//
#include <hip/hip_runtime.h>

#define NN 128   // modes

// ---- whole-wave lane shifts via DPP (wave_shl:1 / wave_shr:1) ----
// bound_ctrl=false + old=src: edge lanes keep own value (zeroed by es coeff).
__device__ __forceinline__ float wshl1(float x) {   // lane i <- lane i+1
    return __int_as_float(__builtin_amdgcn_update_dpp(
        __float_as_int(x), __float_as_int(x), 0x130, 0xf, 0xf, false));
}
__device__ __forceinline__ float wshr1(float x) {   // lane i <- lane i-1
    return __int_as_float(__builtin_amdgcn_update_dpp(
        __float_as_int(x), __float_as_int(x), 0x138, 0xf, 0xf, false));
}

// ---------------- kernel 1: (cos,sin) table ----------------
// tab[j*128+m] = (cos th, sin th) for th = theta_even[j,m]  (261 KB)
__global__ __launch_bounds__(256) void coef_kernel(
    const float* __restrict__ th_ev, float2* __restrict__ tab)
{
    int i = blockIdx.x * 256 + threadIdx.x;
    if (i < 255 * 128) {
        float s, c;
        __sincosf(th_ev[i], &s, &c);
        tab[i] = make_float2(c, s);
    }
}

// ---------------- kernel 2: mesh evolution (table-driven) ----------------
// One wave per column c. Lane l holds rows 4l..4l+3 (4 complex, 8 f32).
// Per layer: ONE dwordx4 load (cos/sin for the lane's two pairs), 24 VALU.
// 8-deep explicit prefetch ring (hand-unrolled; all slot indices static).
__global__ __launch_bounds__(64) void mesh_tab_kernel(
    const float4* __restrict__ tab,        // (255*64) float4 = (c0,s0,c1,s1)
    const float* __restrict__ theta_in,    // (128,)
    const float* __restrict__ theta_out,   // (128,)
    float* __restrict__ out)               // (128,128) f32 = Re(arch)
{
    const int c = blockIdx.x;
    const int l = threadIdx.x;

    const float A  = sqrtf(0.95f * 0.505f);
    const float B  = sqrtf(0.95f * 0.495f);
    const float C2 = sqrtf(0.98f * 0.01f);
    const float S2 = sqrtf(0.98f * 0.99f);

    // branchless corner coeffs: row 0 (l==0, slot v0), row 255 (l==63, slot v3)
    const float ec0 = (l == 0)  ? S2 : C2, es0 = (l == 0)  ? 0.f : S2;
    const float ec3 = (l == 63) ? S2 : C2, es3 = (l == 63) ? 0.f : S2;

    // init: column c after MMI_IN -> rows 2c: A e^{i th}, 2c+1: iB e^{i th}
    float2 v0 = make_float2(0.f, 0.f), v1 = v0, v2 = v0, v3 = v0;
    {
        float s, co;
        __sincosf(theta_in[c], &s, &co);
        float2 e0 = make_float2(A * co, A * s);
        float2 e1 = make_float2(-B * s, B * co);
        if (l == (c >> 1)) {
            if (c & 1) { v2 = e0; v3 = e1; }
            else       { v0 = e0; v1 = e1; }
        }
    }

    const float4* TL = tab + l;     // lane l: float4 at j*64 + l

    float4 tb0 = TL[0*64], tb1 = TL[1*64], tb2 = TL[2*64], tb3 = TL[3*64],
           tb4 = TL[4*64], tb5 = TL[5*64], tb6 = TL[6*64], tb7 = TL[7*64];

    // rotate-then-mix layer: pair (v0,v1) by (t.x,t.y), pair (v2,v3) by (t.z,t.w)
    auto layer = [&](float4 t) {
        float rx = t.x * v0.x - t.y * v0.y;     // e^{i th} * v0
        float ry = t.x * v0.y + t.y * v0.x;
        float qx = t.z * v2.x - t.w * v2.y;     // e^{i th'} * v2
        float qy = t.z * v2.y + t.w * v2.x;
        float2 n0, n1, n2, n3;
        n0.x = A * rx   - B * v1.y;  n0.y = A * ry   + B * v1.x;
        n1.x = A * v1.x - B * ry;    n1.y = A * v1.y + B * rx;
        n2.x = A * qx   - B * v3.y;  n2.y = A * qy   + B * v3.x;
        n3.x = A * v3.x - B * qy;    n3.y = A * v3.y + B * qx;
        v0 = n0; v1 = n1; v2 = n2; v3 = n3;
    };
    auto crossl = [&]() {
        float nx = wshl1(v0.x), ny = wshl1(v0.y);   // lane l+1's v0
        float px = wshr1(v3.x), py = wshr1(v3.y);   // lane l-1's v3
        float2 m0, m1, m2, m3;
        m0.x = ec0 * v0.x - es0 * py;  m0.y = ec0 * v0.y + es0 * px;
        m3.x = ec3 * v3.x - es3 * ny;  m3.y = ec3 * v3.y + es3 * nx;
        m1.x = C2 * v1.x - S2 * v2.y;  m1.y = C2 * v1.y + S2 * v2.x;
        m2.x = C2 * v2.x - S2 * v1.y;  m2.y = C2 * v2.y + S2 * v1.x;
        v0 = m0; v1 = m1; v2 = m2; v3 = m3;
    };

    // layers 0..247 (31 x 8), prefetch distance 8 (clamped reloads are benign)
    for (int j8 = 0; j8 < 248; j8 += 8) {
        int base = (j8 + 8 > 246) ? 0 : (j8 + 8) * 64;   // dummy-safe base
        // exact per-slot prefetch indices (clamped at 254):
        int p0 = j8 + 8,  p1 = j8 + 9,  p2 = j8 + 10, p3 = j8 + 11,
            p4 = j8 + 12, p5 = j8 + 13, p6 = j8 + 14, p7 = j8 + 15;
        if (p7 > 254) { p0 = p0 > 254 ? 254 : p0; p1 = p1 > 254 ? 254 : p1;
                        p2 = p2 > 254 ? 254 : p2; p3 = p3 > 254 ? 254 : p3;
                        p4 = p4 > 254 ? 254 : p4; p5 = p5 > 254 ? 254 : p5;
                        p6 = p6 > 254 ? 254 : p6; p7 = 254; }
        (void)base;
        { float4 t = tb0; tb0 = TL[p0 * 64]; layer(t); crossl(); }  // even
        { float4 t = tb1; tb1 = TL[p1 * 64]; layer(t); }            // odd
        { float4 t = tb2; tb2 = TL[p2 * 64]; layer(t); crossl(); }
        { float4 t = tb3; tb3 = TL[p3 * 64]; layer(t); }
        { float4 t = tb4; tb4 = TL[p4 * 64]; layer(t); crossl(); }
        { float4 t = tb5; tb5 = TL[p5 * 64]; layer(t); }
        { float4 t = tb6; tb6 = TL[p6 * 64]; layer(t); crossl(); }
        { float4 t = tb7; tb7 = TL[p7 * 64]; layer(t); }
    }
    // tail: layers 248..253 from slots 0..5 (no prefetch)
    layer(tb0); crossl();   // 248
    layer(tb1);             // 249
    layer(tb2); crossl();   // 250
    layer(tb3);             // 251
    layer(tb4); crossl();   // 252
    layer(tb5);             // 253

    // layer 254 (slot 6): final diag + MMI_OUT (folded): rows 2l, 2l+1
    float rx = tb6.x * v0.x - tb6.y * v0.y;
    float ry = tb6.x * v0.y + tb6.y * v0.x;
    float qx = tb6.z * v2.x - tb6.w * v2.y;
    float qy = tb6.z * v2.y + tb6.w * v2.x;
    float2 o0, o1;
    o0.x = A * rx - B * v1.y;  o0.y = A * ry + B * v1.x;
    o1.x = A * qx - B * v3.y;  o1.y = A * qy + B * v3.x;

    // diag(d_out) rotation, keep real part
    float2 tho = ((const float2*)theta_out)[l];
    float s0, c0, s1, c1;
    __sincosf(tho.x, &s0, &c0);
    __sincosf(tho.y, &s1, &c1);
    out[(2 * l)     * NN + c] = c0 * o0.x - s0 * o0.y;
    out[(2 * l + 1) * NN + c] = c1 * o1.x - s1 * o1.y;
}

// ---------------- fallback (proven R6-style, self-contained): ws too small ----------------
struct CoefF { float2 a0, b0, a1, b1; };
__device__ __forceinline__ CoefF make_coef_f(float2 th) {
    const float A = sqrtf(0.95f * 0.505f);
    const float B = sqrtf(0.95f * 0.495f);
    float s0, c0, s1, c1;
    __sincosf(th.x, &s0, &c0);
    __sincosf(th.y, &s1, &c1);
    CoefF cf;
    cf.a0 = make_float2(A * c0, A * s0); cf.b0 = make_float2(-B * s0, B * c0);
    cf.a1 = make_float2(A * c1, A * s1); cf.b1 = make_float2(-B * s1, B * c1);
    return cf;
}
__global__ __launch_bounds__(64) void mesh_fallback(
    const float* __restrict__ theta_in, const float* __restrict__ theta_even,
    const float* __restrict__ theta_out, float* __restrict__ out)
{
    const int c = blockIdx.x, l = threadIdx.x;
    const float A  = sqrtf(0.95f * 0.505f);
    const float B  = sqrtf(0.95f * 0.495f);
    const float C2 = sqrtf(0.98f * 0.01f);
    const float S2 = sqrtf(0.98f * 0.99f);
    const float ec0 = (l == 0)  ? S2 : C2, es0 = (l == 0)  ? 0.f : S2;
    const float ec3 = (l == 63) ? S2 : C2, es3 = (l == 63) ? 0.f : S2;
    float2 v0 = make_float2(0.f, 0.f), v1 = v0, v2 = v0, v3 = v0;
    {
        float s, co; __sincosf(theta_in[c], &s, &co);
        if (l == (c >> 1)) {
            float2 e0 = make_float2(A * co, A * s), e1 = make_float2(-B * s, B * co);
            if (c & 1) { v2 = e0; v3 = e1; } else { v0 = e0; v1 = e1; }
        }
    }
    const float2* tev = (const float2*)theta_even + l;
    for (int j = 0; j < 254; ++j) {
        CoefF cf = make_coef_f(tev[j * 64]);
        float2 n0, n1, n2, n3;
        n0.x = cf.a0.x*v0.x - cf.a0.y*v0.y - B*v1.y;  n0.y = cf.a0.x*v0.y + cf.a0.y*v0.x + B*v1.x;
        n1.x = cf.b0.x*v0.x - cf.b0.y*v0.y + A*v1.x;  n1.y = cf.b0.x*v0.y + cf.b0.y*v0.x + A*v1.y;
        n2.x = cf.a1.x*v2.x - cf.a1.y*v2.y - B*v3.y;  n2.y = cf.a1.x*v2.y + cf.a1.y*v2.x + B*v3.x;
        n3.x = cf.b1.x*v2.x - cf.b1.y*v2.y + A*v3.x;  n3.y = cf.b1.x*v2.y + cf.b1.y*v2.x + A*v3.y;
        v0 = n0; v1 = n1; v2 = n2; v3 = n3;
        if ((j & 1) == 0) {
            float nx = wshl1(v0.x), ny = wshl1(v0.y);
            float px = wshr1(v3.x), py = wshr1(v3.y);
            float2 m0, m1, m2, m3;
            m0.x = ec0*v0.x - es0*py;  m0.y = ec0*v0.y + es0*px;
            m3.x = ec3*v3.x - es3*ny;  m3.y = ec3*v3.y + es3*nx;
            m1.x = C2*v1.x - S2*v2.y;  m1.y = C2*v1.y + S2*v2.x;
            m2.x = C2*v2.x - S2*v1.y;  m2.y = C2*v2.y + S2*v1.x;
            v0 = m0; v1 = m1; v2 = m2; v3 = m3;
        }
    }
    CoefF cf = make_coef_f(tev[254 * 64]);
    float2 o0, o1;
    o0.x = cf.a0.x*v0.x - cf.a0.y*v0.y - B*v1.y;  o0.y = cf.a0.x*v0.y + cf.a0.y*v0.x + B*v1.x;
    o1.x = cf.a1.x*v2.x - cf.a1.y*v2.y - B*v3.y;  o1.y = cf.a1.x*v2.y + cf.a1.y*v2.x + B*v3.x;
    float2 tho = ((const float2*)theta_out)[l];
    float s0, c0, s1, c1;
    __sincosf(tho.x, &s0, &c0);
    __sincosf(tho.y, &s1, &c1);
    out[(2 * l)     * NN + c] = c0 * o0.x - s0 * o0.y;
    out[(2 * l + 1) * NN + c] = c1 * o1.x - s1 * o1.y;
}

extern "C" void kernel_launch(void* const* d_in, const int* in_sizes, int n_in,
                              void* d_out, int out_size, void* d_ws, size_t ws_size,
                              hipStream_t stream) {
    // Identify inputs by SIZE: theta_even is the unique large (32640) array;
    // the two 128-elem arrays keep relative order (theta_in before theta_out).
    int ev = 0;
    for (int i = 0; i < n_in; ++i) if (in_sizes[i] > 1000) ev = i;
    int a = -1, b = -1;
    for (int i = 0; i < n_in; ++i) {
        if (i == ev) continue;
        if (a < 0) a = i; else if (b < 0) b = i;
    }
    const float* th_in  = (const float*)d_in[a];
    const float* th_ev  = (const float*)d_in[ev];
    const float* th_out = (const float*)d_in[b];

    const size_t tab_bytes = (size_t)255 * 128 * sizeof(float2);   // 261120
    if (ws_size >= tab_bytes) {
        float2* tab = (float2*)d_ws;
        coef_kernel<<<dim3(128), dim3(256), 0, stream>>>(th_ev, tab);
        mesh_tab_kernel<<<dim3(NN), dim3(64), 0, stream>>>((const float4*)tab, th_in, th_out, (float*)d_out);
    } else {
        mesh_fallback<<<dim3(NN), dim3(64), 0, stream>>>(th_in, th_ev, th_out, (float*)d_out);
    }
}